// Round 2
// baseline (1809.323 us; speedup 1.0000x reference)
//
#include <hip/hip_runtime.h>

typedef _Float16 h8 __attribute__((ext_vector_type(8)));
typedef float v4f __attribute__((ext_vector_type(4)));
typedef unsigned long long u64;

#define B_  256
#define T_  512
#define I_  64
#define H_  512

// workspace layout (bytes)
#define OFF_W16   0                                   // [2048][512] f16
#define OFF_WIH   (OFF_W16 + 2048*512*2)              // [2048][64]  f16
#define OFF_BIAS  (OFF_WIH + 2048*64*2)               // [2048]      f32 (b_ih+b_hh)
#define OFF_X16   (OFF_BIAS + 2048*4)                 // [512][256][64] f16 (transposed)
#define OFF_H0    (OFF_X16 + 512*256*64*2)            // [256][512] f16
#define OFF_H1    (OFF_H0 + 256*512*2)                // [256][512] f16
#define OFF_SNT   (OFF_H1 + 256*512*2)                // sentinels [16 bg][8 cg][4 wave] u32

__device__ __forceinline__ float sigf(float x) {
    float e = __builtin_amdgcn_exp2f(-1.442695041f * x);
    return __builtin_amdgcn_rcpf(1.f + e);
}
__device__ __forceinline__ float tanhf_(float x) {
    float e = __builtin_amdgcn_exp2f(2.885390082f * x);  // exp(2x)
    return 1.f - 2.f * __builtin_amdgcn_rcpf(e + 1.f);
}

__global__ void prep_w(const float* __restrict__ Wih, const float* __restrict__ Whh,
                       const float* __restrict__ bih, const float* __restrict__ bhh,
                       _Float16* __restrict__ W16, _Float16* __restrict__ Wih16,
                       float* __restrict__ bias, _Float16* __restrict__ h0,
                       unsigned* __restrict__ snt) {
    int idx = blockIdx.x * 256 + threadIdx.x;          // grid covers 2048*512
    W16[idx] = (_Float16)Whh[idx];
    if (idx < 2048 * 64)  Wih16[idx] = (_Float16)Wih[idx];
    if (idx < 2048)       bias[idx] = bih[idx] + bhh[idx];
    // h0 zeros + sentinels must be visible at the IF$ coherence point
    if (idx < 32768)
        __hip_atomic_store((u64*)h0 + idx, 0ull,
                           __ATOMIC_RELAXED, __HIP_MEMORY_SCOPE_AGENT);
    if (idx < 512)
        __hip_atomic_store(snt + idx, 0u, __ATOMIC_RELAXED, __HIP_MEMORY_SCOPE_AGENT);
}

__global__ void prep_x(const float* __restrict__ x, _Float16* __restrict__ x16) {
    int idx = blockIdx.x * 256 + threadIdx.x;          // grid covers 512*256*64
    int t = idx >> 14;                                  // / (256*64)
    int rem = idx & 16383;
    int b = rem >> 6;
    int i = rem & 63;
    x16[idx] = (_Float16)x[((size_t)b * T_ + t) * I_ + i];
}

// 128 wgs: 16 batch-groups x 8 col-groups. wg owns 16 batch rows x 64 h-cols.
// Wave wv owns h-cols J0+16wv..+15 for ALL FOUR gates -> i,f,g,o for a cell
// land in the same lane/reg of 4 accumulators: LSTM cell runs in registers,
// no S staging. A-tile (h rows + x) staged once per wg in swizzled
// chunk-major LDS layout shared by all 4 waves.
// blockIdx = bg + 16*cg -> the 8 wgs of a bg share blockIdx%8 (same XCD).
__launch_bounds__(256, 1)
__global__ void lstm_k(const _Float16* __restrict__ W16, const _Float16* __restrict__ Wih16,
                       const float* __restrict__ bias, const _Float16* __restrict__ x16,
                       _Float16* __restrict__ h0, _Float16* __restrict__ h1,
                       unsigned* __restrict__ snt) {
    // A: 9 regions x 2048B. region = col4>>4 (col4 = 8B unit = 4 f16 cols).
    // byte(row, col4) = (col4>>4)*2048 + row*128 + (((col4&15)>>1 ^ (row&7))<<4)
    //                   + (col4&1)*8   -- XOR swizzle keeps writes AND
    //                   ds_read_b128 fragment reads bank-balanced.
    __shared__ __align__(16) char A[9 * 2048];   // 18 KiB

    const int tid  = threadIdx.x;
    const int lane = tid & 63;
    const int wv   = tid >> 6;        // wave = col sub-block (0..3)
    const int bg   = blockIdx.x & 15; // batch group (XCD-affine)
    const int cg   = blockIdx.x >> 4; // column group 0..7
    const int B0   = bg * 16;
    const int J0   = cg * 64;         // h-column base
    const int r    = lane & 15;
    const int q    = lane >> 4;

    // --- hoist weight B-fragments: 4 gates x 18 K-chunks (288 VGPRs) ---
    h8 bfrag[4][18];
    float biasv[4];
#pragma unroll
    for (int g = 0; g < 4; ++g) {
        const int wrow = g * H_ + J0 + wv * 16 + r;     // gate-col index
#pragma unroll
        for (int kk = 0; kk < 16; ++kk)
            bfrag[g][kk] = *(const h8*)(W16 + (size_t)wrow * H_ + kk * 32 + q * 8);
#pragma unroll
        for (int kk = 16; kk < 18; ++kk)
            bfrag[g][kk] = *(const h8*)(Wih16 + (size_t)wrow * I_ + (kk - 16) * 32 + q * 8);
        biasv[g] = bias[wrow];
    }

    // staging ownership: thread -> (row srow, 8B-units sc+16i, i=0..8)
    const int srow = tid >> 4;        // 0..15
    const int sc   = tid & 15;
    char* const wp = A + srow * 128 + (((sc >> 1) ^ (srow & 7)) << 4) + ((sc & 1) << 3);
    // ds_read bases: chunk kk even uses rbE, odd rbE^64 ((4|q)^m == (q^m)^4)
    const int rbE = r * 128 + ((q ^ (r & 7)) << 4);
    const int rbO = rbE ^ 64;

    // cell state: lane owns rows B0+4q+reg, col J0+16wv+r
    float cc[4] = {0.f, 0.f, 0.f, 0.f};

    const u64* const xp = (const u64*)x16;
    u64 xv = xp[((size_t)(B0 + srow)) * 16 + sc];       // x unit for s=0

    unsigned* const mysnt = snt + bg * 32;              // 32 sentinels, 128B/bg

    for (int s = 0; s < T_; ++s) {
        const _Float16* hp = (s & 1) ? h1 : h0;
        _Float16*       hn = (s & 1) ? h0 : h1;

        // ---- phase A: h (device-scope) + prefetched x -> swizzled LDS ----
        {
            // h row = 512 f16 = 1024 B = 128 u64 units (NOT 64 -- r1 bugfix)
            const u64* hp64 = (const u64*)hp + (size_t)(B0 + srow) * 128;
            u64 hv[8];
#pragma unroll
            for (int i = 0; i < 8; ++i)
                hv[i] = __hip_atomic_load(hp64 + sc + 16 * i,
                                          __ATOMIC_RELAXED, __HIP_MEMORY_SCOPE_AGENT);
#pragma unroll
            for (int i = 0; i < 8; ++i)
                *(u64*)(wp + i * 2048) = hv[i];
            *(u64*)(wp + 8 * 2048) = xv;               // x chunks 16,17 (region 8)
        }
        __syncthreads();

        // x prefetch for s+1 (after barrier so its drain isn't on this path)
        if (s + 1 < T_)
            xv = xp[((size_t)(s + 1) * B_ + B0 + srow) * 16 + sc];

        // ---- phase B: K = 18 chunks of 32; one A-frag feeds all 4 gates ----
        v4f a0 = {0,0,0,0}, a1 = {0,0,0,0}, a2 = {0,0,0,0}, a3 = {0,0,0,0};
#pragma unroll
        for (int kk = 0; kk < 18; ++kk) {
            const h8 av = *(const h8*)(A + (kk >> 1) * 2048 + ((kk & 1) ? rbO : rbE));
            a0 = __builtin_amdgcn_mfma_f32_16x16x32_f16(av, bfrag[0][kk], a0, 0, 0, 0);
            a1 = __builtin_amdgcn_mfma_f32_16x16x32_f16(av, bfrag[1][kk], a1, 0, 0, 0);
            a2 = __builtin_amdgcn_mfma_f32_16x16x32_f16(av, bfrag[2][kk], a2, 0, 0, 0);
            a3 = __builtin_amdgcn_mfma_f32_16x16x32_f16(av, bfrag[3][kk], a3, 0, 0, 0);
        }

        // ---- phase C: LSTM cell fully in registers; h' as 4x2B stores ----
        // C/D: col = lane&15 (h-col), row = q*4+reg (batch)  [m89-verified]
        {
            unsigned short* hw = (unsigned short*)hn
                               + (size_t)(B0 + q * 4) * H_ + J0 + wv * 16 + r;
#pragma unroll
            for (int reg = 0; reg < 4; ++reg) {
                float iv = sigf  (a0[reg] + biasv[0]);
                float fv = sigf  (a1[reg] + biasv[1]);
                float gv = tanhf_(a2[reg] + biasv[2]);
                float ov = sigf  (a3[reg] + biasv[3]);
                cc[reg] = fv * cc[reg] + iv * gv;
                union { _Float16 f; unsigned short u; } cv;
                cv.f = (_Float16)(ov * tanhf_(cc[reg]));
                __hip_atomic_store(hw + (size_t)reg * H_, cv.u,
                                   __ATOMIC_RELAXED, __HIP_MEMORY_SCOPE_AGENT);
            }
        }

        // ---- per-wave release: drain own stores, then sentinel (no RMW) ----
        asm volatile("s_waitcnt vmcnt(0)" ::: "memory");
        if (lane == 0)
            __hip_atomic_store(mysnt + cg * 4 + wv, (unsigned)(s + 1),
                               __ATOMIC_RELAXED, __HIP_MEMORY_SCOPE_AGENT);

        // ---- wait all 32 producer-waves of this bg (wave-0 parallel poll) ----
        if (tid < 32) {
            const unsigned tgt = (unsigned)(s + 1);
            int guard = 0;
            while (__hip_atomic_load(mysnt + tid,
                                     __ATOMIC_RELAXED, __HIP_MEMORY_SCOPE_AGENT) < tgt) {
                __builtin_amdgcn_s_sleep(1);
                if (++guard > (1 << 17)) break;   // anti-hang: fail loud, not silent
            }
        }
        __syncthreads();
    }
}

__global__ void fc_k(const _Float16* __restrict__ hlast, const float* __restrict__ Wfc,
                     const float* __restrict__ bfc, float* __restrict__ out) {
    int b = blockIdx.x;
    int lane = threadIdx.x;   // 64 threads
    // h was written with device-scope stores (bypassing L2) -> read device-scope
    const u64* hp64 = (const u64*)(hlast + (size_t)b * H_);
    union { _Float16 f[4]; u64 u; } p0, p1;
    p0.u = __hip_atomic_load(hp64 + lane * 2,     __ATOMIC_RELAXED, __HIP_MEMORY_SCOPE_AGENT);
    p1.u = __hip_atomic_load(hp64 + lane * 2 + 1, __ATOMIC_RELAXED, __HIP_MEMORY_SCOPE_AGENT);
    float sum = 0.f;
#pragma unroll
    for (int j = 0; j < 4; ++j) sum += (float)p0.f[j] * Wfc[lane * 8 + j];
#pragma unroll
    for (int j = 0; j < 4; ++j) sum += (float)p1.f[j] * Wfc[lane * 8 + 4 + j];
    for (int off = 32; off; off >>= 1) sum += __shfl_down(sum, off);
    if (lane == 0) out[b] = sum + bfc[0];
}

extern "C" void kernel_launch(void* const* d_in, const int* in_sizes, int n_in,
                              void* d_out, int out_size, void* d_ws, size_t ws_size,
                              hipStream_t stream) {
    (void)in_sizes; (void)n_in; (void)out_size; (void)ws_size;
    const float* x   = (const float*)d_in[0];
    const float* Wih = (const float*)d_in[1];
    const float* Whh = (const float*)d_in[2];
    const float* bih = (const float*)d_in[3];
    const float* bhh = (const float*)d_in[4];
    const float* Wfc = (const float*)d_in[5];
    const float* bfc = (const float*)d_in[6];
    float* out = (float*)d_out;

    char* ws = (char*)d_ws;
    _Float16* W16   = (_Float16*)(ws + OFF_W16);
    _Float16* Wih16 = (_Float16*)(ws + OFF_WIH);
    float*    biasf = (float*)(ws + OFF_BIAS);
    _Float16* x16   = (_Float16*)(ws + OFF_X16);
    _Float16* h0b   = (_Float16*)(ws + OFF_H0);
    _Float16* h1b   = (_Float16*)(ws + OFF_H1);
    unsigned* sntb  = (unsigned*)(ws + OFF_SNT);

    hipLaunchKernelGGL(prep_w, dim3((2048 * 512) / 256), dim3(256), 0, stream,
                       Wih, Whh, bih, bhh, W16, Wih16, biasf, h0b, sntb);
    hipLaunchKernelGGL(prep_x, dim3((512 * 256 * 64) / 256), dim3(256), 0, stream, x, x16);
    hipLaunchKernelGGL(lstm_k, dim3(128), dim3(256), 0, stream,
                       W16, Wih16, biasf, x16, h0b, h1b, sntb);
    // T=512 even: last write went to buffer 0
    hipLaunchKernelGGL(fc_k, dim3(256), dim3(64), 0, stream, h0b, Wfc, bfc, out);
}